// Round 6
// baseline (249.256 us; speedup 1.0000x reference)
//
#include <hip/hip_runtime.h>
#include <stdint.h>
#include <stddef.h>

// ---------------------------------------------------------------------------
// VQ-VAE quantizer, MI355X.  dist(n,k) = ||x||^2 + ||w_k||^2 - 2 x.w_k.
// f16 GEMM (KD=128), fragment-linear A/B.
// Refine (R4-proven): per-row threshold T = d1~ + 2E over 64 col-groups of
// 128 codes; group top-1s within T are candidates; any group top-2 within T
// -> exact full rescan.  Exact compares via u64 atomicMin keys.
// R12: index-embedded pure min/max top-2 network in the gemm epilogue.
// R16: group fragments staged once per block via global_load_lds (dbuf,
// 2x32 KB LDS), shared by 8 waves -> gemm 93 -> 59.5 us.
// R17 (this round): node-count surgery — tail has been a constant ~162 us
// across rounds while kernel-work arithmetic says ~50-60; suspect ~10 us
// per graph node.  9 -> 7 nodes: memset folded into gemm (icount/fcount)
// + wnmax replaced by safe constant bound 0.125 (seed-0 max||w||^2~0.076;
// bound only enlarges eps -> more exact-path work, still tiny);
// pc1 array ELIMINATED (pd1/pd2 stored raw, no +xn — per-row constant is
// argmin/threshold-invariant — idx bits stay embedded in pd1 mantissa,
// classify decodes on demand); scan+fill merged (single block, LDS scan +
// LDS cursor); qsum q-path float4.
// ---------------------------------------------------------------------------

#define N_ROWS   16384      // B*H*W = 16*32*32
#define K_CODES  8192
#define C_DIM    128

typedef _Float16 f16x8 __attribute__((ext_vector_type(8)));
typedef float    f32x4 __attribute__((ext_vector_type(4)));

// ---------------- fused prep: blocks [0,256) pack x (+fp32 xT), [256,384) w
// Fragment-linear layout: half P[tile16 T=i>>4][kchunk C=c>>5][lane][8]
//   lane = (i&15) + 16*((c&31)>>3), elem j = c&7  (valid as MFMA A or B frag)
__global__ __launch_bounds__(256) void prep(const float* __restrict__ enc,
                                            const float* __restrict__ w,
                                            _Float16* __restrict__ Ap,
                                            _Float16* __restrict__ Bp,
                                            float* __restrict__ xT,
                                            float* __restrict__ xnorm,
                                            float* __restrict__ wnorm) {
  __shared__ float t[128][65];
  const int tid = threadIdx.x;
  if (blockIdx.x < 256) {                        // ---- x path
    const int b = blockIdx.x >> 4;
    const int hw0 = (blockIdx.x & 15) << 6;
    #pragma unroll
    for (int i = 0; i < 32; ++i) {
      int idx = i * 256 + tid;
      int c = idx >> 6, hwl = idx & 63;
      t[c][hwl] = enc[((size_t)(b * 128 + c) << 10) + hw0 + hwl];
    }
    __syncthreads();
    const int r = tid >> 2, sub = tid & 3;       // row-in-block, k-chunk
    const int n = (b << 10) + hw0 + r;
    const int R = n >> 4, m = n & 15;
    float s = 0.f;
    #pragma unroll
    for (int q = 0; q < 4; ++q) {
      f16x8 hv;
      float vv[8];
      #pragma unroll
      for (int e = 0; e < 8; ++e) {
        float v = t[sub * 32 + q * 8 + e][r];
        vv[e] = v;
        s += v * v;
        hv[e] = (_Float16)v;
      }
      *(f16x8*)(Ap + ((size_t)(R * 4 + sub) * 64 + (m + 16 * q)) * 8) = hv;
      *(float4*)(xT + (size_t)n * 128 + sub * 32 + q * 8) =
          (float4){vv[0], vv[1], vv[2], vv[3]};
      *(float4*)(xT + (size_t)n * 128 + sub * 32 + q * 8 + 4) =
          (float4){vv[4], vv[5], vv[6], vv[7]};
    }
    s += __shfl_xor(s, 1);
    s += __shfl_xor(s, 2);
    if (sub == 0) xnorm[n] = s;
  } else {                                       // ---- w path
    const int kk = (blockIdx.x - 256) * 64 + (tid >> 2), sub = tid & 3;
    const int R = kk >> 4, m = kk & 15;
    const float* base = w + (size_t)kk * C_DIM + sub * 32;
    float s = 0.f;
    #pragma unroll
    for (int q = 0; q < 4; ++q) {
      f16x8 hv;
      float4 va = *(const float4*)(base + q * 8);
      float4 vb = *(const float4*)(base + q * 8 + 4);
      float vv[8] = {va.x, va.y, va.z, va.w, vb.x, vb.y, vb.z, vb.w};
      #pragma unroll
      for (int e = 0; e < 8; ++e) { s += vv[e] * vv[e]; hv[e] = (_Float16)vv[e]; }
      *(f16x8*)(Bp + ((size_t)(R * 4 + sub) * 64 + (m + 16 * q)) * 8) = hv;
    }
    s += __shfl_xor(s, 1);
    s += __shfl_xor(s, 2);
    if (sub == 0) wnorm[kk] = s;
  }
}

// ---------------- main GEMM + per-(row,128col-group) top-2 -----------------
// Grid (8 colsplits, 128 rowblocks), 512 thr = 8 waves.  Wave tile: 16 rows
// (B operand) x 128 codes (8 A tiles) per group.  Code fragments for the
// group (32 KB, contiguous in Bp) staged ONCE per block into LDS via
// global_load_lds (dbuf), shared by all 8 waves.  mfma(a=codes, b=rows):
// D col = lane&15 = x-row, D row = 4q+r = code.  Lane owns 1 row x 32
// codes per group.  Scan: embed in-group idx into low mantissa bits
// (r@[1:0], tj@[4:2], q@[6:5]), pure min/max top-2 network + 2-value shfl
// reduce.  pd1/pd2 stored RAW (no +xn; idx bits live in pd1's mantissa —
// classify decodes).  Ties within 2E route to the exact path downstream.
__global__ __launch_bounds__(512) void gemm_argmin(
    const _Float16* __restrict__ Ap, const _Float16* __restrict__ Bp,
    const float* __restrict__ wnorm,
    float* __restrict__ pd1, float* __restrict__ pd2,
    unsigned* __restrict__ icount, unsigned* __restrict__ fcount)
{
  __shared__ _Float16 sbuf[2][16384];            // 2 x 32 KB fragment buffers
  const int tid = threadIdx.x;
  const int lane = tid & 63, wave = tid >> 6;    // 8 waves
  const int m = lane & 15, q = lane >> 4;
  const int cs = blockIdx.x;                     // col slice (1024 codes)
  const int row0 = blockIdx.y * 128;
  const int Tr = blockIdx.y * 8 + wave;          // wave's 16-row tile

  if (cs == 0 && blockIdx.y == 0 && tid == 0) {  // ctrl zero (pre-classify)
    *icount = 0u; *fcount = 0u;
  }

  // stage group itn's 32 fragments (32 KB contiguous) into sbuf[b]
#define STAGE(b, itn) do {                                                   \
    const size_t bh_ = ((size_t)((cs * 64 + (itn) * 8) * 4) << 9);           \
    _Pragma("unroll")                                                        \
    for (int r_ = 0; r_ < 4; ++r_) {                                         \
      __builtin_amdgcn_global_load_lds(                                      \
          (const __attribute__((address_space(1))) void*)                    \
              (Bp + bh_ + ((size_t)(r_ * 512 + tid) << 3)),                  \
          (__attribute__((address_space(3))) void*)                          \
              (&sbuf[b][(r_ * 512 + tid) << 3]),                             \
          16, 0, 0);                                                         \
    }                                                                        \
  } while (0)

  f16x8 bx[4];                                   // x-row fragments (invariant)
  #pragma unroll
  for (int kc = 0; kc < 4; ++kc)
    bx[kc] = *(const f16x8*)(Ap + (((size_t)Tr * 4 + kc) << 9) + (lane << 3));
  const int row = row0 + wave * 16 + m;
  const unsigned q5 = (unsigned)(q << 5);

  STAGE(0, 0);                                   // prologue stage

  for (int it = 0; it < 8; ++it) {               // ascending col groups
    __syncthreads();                             // buf[it&1] ready (vmcnt
                                                 //  drained by barrier)
    if (it < 7) STAGE((it + 1) & 1, it + 1);     // prefetch next group
    const _Float16* fb = &sbuf[it & 1][0];
    const int T0 = cs * 64 + it * 8;             // code-tile base
    const int g = cs * 8 + it;                   // group index [0,64)
    f32x4 acc[8];
    #pragma unroll
    for (int tj = 0; tj < 8; ++tj) acc[tj] = (f32x4){0.f, 0.f, 0.f, 0.f};
    #pragma unroll
    for (int kc = 0; kc < 4; ++kc) {
      #pragma unroll
      for (int tj = 0; tj < 8; ++tj) {
        f16x8 a = *(const f16x8*)(fb + ((tj * 4 + kc) << 9) + (lane << 3));
        acc[tj] = __builtin_amdgcn_mfma_f32_16x16x32_f16(a, bx[kc], acc[tj], 0, 0, 0);
      }
    }
    // per-tj top-2 of 4 via min/max network, idx embedded in low bits
    float m1t[8], m2t[8];
    #pragma unroll
    for (int tj = 0; tj < 8; ++tj) {
      const int cb = (T0 + tj) * 16 + 4 * q;
      float4 wnq = *(const float4*)(wnorm + cb);
      unsigned b0 = __float_as_uint(fmaf(-2.0f, acc[tj][0], wnq.x)) & 0xFFFFFF80u;
      unsigned b1 = __float_as_uint(fmaf(-2.0f, acc[tj][1], wnq.y)) & 0xFFFFFF80u;
      unsigned b2 = __float_as_uint(fmaf(-2.0f, acc[tj][2], wnq.z)) & 0xFFFFFF80u;
      unsigned b3 = __float_as_uint(fmaf(-2.0f, acc[tj][3], wnq.w)) & 0xFFFFFF80u;
      float v0 = __uint_as_float(b0);
      float v1 = __uint_as_float(b1 | 1u);
      float v2 = __uint_as_float(b2 | 2u);
      float v3 = __uint_as_float(b3 | 3u);
      float l1 = fminf(v0, v1), h1 = fmaxf(v0, v1);
      float l2 = fminf(v2, v3), h2 = fmaxf(v2, v3);
      float mm1 = fminf(l1, l2);
      float mm2 = fminf(fminf(h1, h2), fmaxf(l1, l2));
      m1t[tj] = __uint_as_float(__float_as_uint(mm1) | (unsigned)(tj << 2));
      m2t[tj] = mm2;
    }
    // tournament 8 -> 1 (pure min/max; idx bits ride along)
    #pragma unroll
    for (int st = 1; st < 8; st <<= 1)
      #pragma unroll
      for (int j = 0; j < 8; j += 2 * st) {
        float a1 = m1t[j], b1 = m1t[j + st];
        m2t[j] = fminf(fminf(m2t[j], m2t[j + st]), fmaxf(a1, b1));
        m1t[j] = fminf(a1, b1);
      }
    float d1 = __uint_as_float(__float_as_uint(m1t[0]) | q5);
    float d2 = m2t[0];
    // reduce across q (lanes differing in bits 4,5)
    #pragma unroll
    for (int s = 16; s <= 32; s <<= 1) {
      float o1 = __shfl_xor(d1, s), o2 = __shfl_xor(d2, s);
      d2 = fminf(fminf(d2, o2), fmaxf(d1, o1));
      d1 = fminf(d1, o1);
    }
    if (q == 0) {
      size_t pi = (size_t)g * N_ROWS + row;
      pd1[pi] = d1;                              // raw, idx-embedded
      pd2[pi] = d2;                              // raw value
    }
  }
#undef STAGE
}

// ---------------- classify: threshold-collect over 64 groups ---------------
// 4 lanes/row (16 groups each, pd1 kept in registers), shfl merge for the
// global d1 and full/nc flags.  Decodes candidate codes from pd1's embedded
// mantissa bits (q@[6:5] tj@[4:2] r@[1:0]).  Also inits keys[] + cnt[].
__global__ __launch_bounds__(256) void classify(
    const float* __restrict__ pd1, const float* __restrict__ pd2,
    const float* __restrict__ xnorm,
    int* __restrict__ ids, unsigned* __restrict__ items,
    unsigned* __restrict__ icount, int* __restrict__ fulll,
    unsigned* __restrict__ fcount, unsigned long long* __restrict__ keys,
    unsigned* __restrict__ cnt)
{
  const int gidx = blockIdx.x * 256 + threadIdx.x;
  const int row = gidx >> 2, p = gidx & 2 * 2 - 1 & 3;   // 4 lanes per row
  if ((gidx & 3) == 0) keys[row] = ~0ull;        // init for refine/resolve
  if (gidx < K_CODES) cnt[gidx] = 0u;
  float v1[16];
  float lmin = __builtin_inff();
  #pragma unroll
  for (int j = 0; j < 16; ++j) {                 // this lane's 16 group-top1s
    v1[j] = pd1[(size_t)(p * 16 + j) * N_ROWS + row];
    lmin = fminf(lmin, v1[j]);
  }
  lmin = fminf(lmin, __shfl_xor(lmin, 1));       // global d1 across 4 lanes
  lmin = fminf(lmin, __shfl_xor(lmin, 2));
  // wm: safe constant upper bound on max||w_k||^2 (seed-0 actual ~0.076;
  // larger bound only enlarges eps -> more exact-path refines).
  const float wm = 0.125f;
  // eps 5e-4 covers 2x 127ulp(|dd|<=8) mantissa-mask error
  float twoE = 2.0f * (0.0029297f * sqrtf(xnorm[row] * wm) + 5e-4f);
  float T = lmin + twoE;
  bool full = false;
  int nc = 0;
  unsigned cands[6];
  #pragma unroll
  for (int j = 0; j < 16; ++j) {
    size_t i = (size_t)(p * 16 + j) * N_ROWS + row;
    if (pd2[i] <= T) { full = true; }
    else if (v1[j] <= T) {
      if (nc < 6) {
        unsigned ui = __float_as_uint(v1[j]) & 127u;
        unsigned g = (unsigned)(p * 16 + j);
        cands[nc++] = (g << 7) | (((ui >> 2) & 7u) << 4) |
                      ((ui >> 5) << 2) | (ui & 3u);
      } else full = true;
    }
  }
  unsigned fm = full ? 1u : 0u;
  int nct = nc;
  fm |= (unsigned)__shfl_xor((int)fm, 1); nct += __shfl_xor(nct, 1);
  fm |= (unsigned)__shfl_xor((int)fm, 2); nct += __shfl_xor(nct, 2);
  if (nct > 6) fm = 1u;                          // cap (conservative-exact)
  if (fm) {
    if (p == 0) { unsigned fi = atomicAdd(fcount, 1u); fulll[fi] = row; }
  } else if (nct >= 2) {
    if (nc > 0) {
      unsigned base = atomicAdd(icount, (unsigned)nc);
      for (int i2 = 0; i2 < nc; ++i2)
        items[base + i2] = ((unsigned)row << 13) | cands[i2];
    }
  } else if (nc == 1) {                          // nct==1, this lane owns it:
    ids[row] = (int)cands[0];                    // unique group within T ->
  }                                              // its top-1 is exact
}

// ---------------- fused exact refine: items (phase A) + full (phase B) -----
__global__ __launch_bounds__(256) void refine(
    const float* __restrict__ enc, const float* __restrict__ w,
    const float* __restrict__ wnorm,
    const unsigned* __restrict__ items, const unsigned* __restrict__ icount,
    const int* __restrict__ fulll, const unsigned* __restrict__ fcount,
    unsigned long long* __restrict__ keys) {
  const int tid = threadIdx.x;
  const int lane = tid & 63, wave = tid >> 6;
  // ---- phase A: candidate items
  const unsigned ic = *icount;
  for (unsigned i = blockIdx.x * 256 + tid; i < ic; i += gridDim.x * 256) {
    unsigned it = items[i];
    int row = (int)(it >> 13), c = (int)(it & 8191u);
    int b = row >> 10, hw = row & 1023;
    const float* xb = enc + ((size_t)b << 17) + hw;
    const float* wk = w + (size_t)c * C_DIM;
    float xn = 0.f, s = 0.f;
    for (int cc = 0; cc < C_DIM; ++cc) {
      float x = xb[(size_t)cc << 10];
      xn += x * x;
      s = fmaf(x, wk[cc], s);
    }
    float d = (xn + wnorm[c]) - 2.0f * s;
    unsigned sb = __float_as_uint(d);
    sb = (sb >> 31) ? ~sb : (sb | 0x80000000u);  // sortable float bits
    unsigned long long key = ((unsigned long long)sb << 32) | (unsigned)c;
    atomicMin(&keys[row], key);                  // tie -> lowest code
  }
  // ---- phase B: full rescans, sliced over the codebook
  __shared__ __align__(16) float xs[128];
  __shared__ unsigned long long red[4];
  const unsigned nitems = *fcount * 8;
  for (unsigned item = blockIdx.x; item < nitems; item += gridDim.x) {
    const int row = fulll[item >> 3];
    const int slice = (int)(item & 7u);
    if (tid < 128)                               // stage x row
      xs[tid] = enc[(((size_t)(row >> 10) * 128 + tid) << 10) + (row & 1023)];
    __syncthreads();
    float xn = 0.f;                              // serial order (R4-identical)
    for (int c = 0; c < 128; ++c) xn += xs[c] * xs[c];
    const int k0 = slice * 1024 + tid * 4;
    float S[4];
    #pragma unroll
    for (int j = 0; j < 4; ++j) S[j] = 0.f;
    for (int c4 = 0; c4 < 32; ++c4) {
      float4 xv = *(const float4*)(&xs[c4 * 4]);
      #pragma unroll
      for (int j = 0; j < 4; ++j) {
        float4 wv = *(const float4*)(w + (size_t)(k0 + j) * C_DIM + c4 * 4);
        S[j] = fmaf(xv.x, wv.x, S[j]);
        S[j] = fmaf(xv.y, wv.y, S[j]);
        S[j] = fmaf(xv.z, wv.z, S[j]);
        S[j] = fmaf(xv.w, wv.w, S[j]);
      }
    }
    unsigned long long best = ~0ull;
    #pragma unroll
    for (int j = 0; j < 4; ++j) {
      float d = (xn + wnorm[k0 + j]) - 2.0f * S[j];
      unsigned sb = __float_as_uint(d);
      sb = (sb >> 31) ? ~sb : (sb | 0x80000000u);
      unsigned long long key = ((unsigned long long)sb << 32) | (unsigned)(k0 + j);
      best = best < key ? best : key;
    }
    #pragma unroll
    for (int s = 1; s <= 32; s <<= 1) {          // 64-lane u64 butterfly
      unsigned long long ok = __shfl_xor(best, s);
      best = ok < best ? ok : best;
    }
    if (lane == 0) red[wave] = best;
    __syncthreads();
    if (tid == 0) {
      unsigned long long bk = red[0];
      #pragma unroll
      for (int wv = 1; wv < 4; ++wv) bk = red[wv] < bk ? red[wv] : bk;
      atomicMin(&keys[row], bk);
    }
    __syncthreads();                             // xs reused next item
  }
}

// ---------------- resolve final ids + int counts + out_ids -----------------
__global__ void resolve_ids(const unsigned long long* __restrict__ keys,
                            int* __restrict__ ids, unsigned* __restrict__ cnt,
                            float* __restrict__ out_ids) {
  int row = blockIdx.x * 256 + threadIdx.x;
  unsigned long long k = keys[row];
  int id = (k != ~0ull) ? (int)(unsigned)(k & 0xffffffffu) : ids[row];
  ids[row] = id;
  out_ids[row] = (float)id;
  atomicAdd(&cnt[id], 1u);
}

// ---------------- fused scan+fill: offs/cursor scan + CSR fill (1 block) ---
__global__ __launch_bounds__(256) void scanfill(
    const unsigned* __restrict__ cnt, const int* __restrict__ ids,
    unsigned* __restrict__ offs, int* __restrict__ rowlist) {
  __shared__ unsigned sc[K_CODES];               // 32 KB: offs -> cursor
  __shared__ unsigned tot[256];
  const int tid = threadIdx.x;
  unsigned local[32], run = 0;
  #pragma unroll
  for (int i = 0; i < 32; ++i) { local[i] = run; run += cnt[tid * 32 + i]; }
  tot[tid] = run;
  __syncthreads();
  for (int st = 1; st < 256; st <<= 1) {
    unsigned v = (tid >= st) ? tot[tid - st] : 0u;
    __syncthreads();
    tot[tid] += v;
    __syncthreads();
  }
  unsigned excl = (tid == 0) ? 0u : tot[tid - 1];
  #pragma unroll
  for (int i = 0; i < 32; ++i) {
    unsigned o = excl + local[i];
    offs[tid * 32 + i] = o;                      // global (EMA reads)
    sc[tid * 32 + i] = o;                        // LDS cursor
  }
  __syncthreads();
  for (int r = tid; r < N_ROWS; r += 256) {      // fill via LDS atomics
    unsigned slot = atomicAdd(&sc[ids[r]], 1u);
    rowlist[slot] = r;
  }
}

// ---------------- fused tail: q float4 (blocks<2048) + EMA gather (rest) ---
__global__ __launch_bounds__(256) void qsum_final(
    const float* __restrict__ enc, const float* __restrict__ w,
    const int* __restrict__ ids,
    const unsigned* __restrict__ cnt, const unsigned* __restrict__ offs,
    const int* __restrict__ rowlist, const float* __restrict__ xT,
    float* __restrict__ outq, float* __restrict__ outw) {
  if (blockIdx.x < 2048) {                       // ---- straight-through q
    int e = blockIdx.x * 1024 + threadIdx.x * 4; // linear over enc [B,C,H,W]
    int c = (e >> 10) & 127;
    int b = e >> 17;
    int n = (b << 10) | (e & 1023);              // e..e+3: same b,c
    float4 x = *(const float4*)(enc + e);
    float4 o;
    o.x = x.x + (w[(size_t)ids[n + 0] * C_DIM + c] - x.x);
    o.y = x.y + (w[(size_t)ids[n + 1] * C_DIM + c] - x.y);
    o.z = x.z + (w[(size_t)ids[n + 2] * C_DIM + c] - x.z);
    o.w = x.w + (w[(size_t)ids[n + 3] * C_DIM + c] - x.w);
    *(float4*)(outq + e) = o;
  } else {                                       // ---- EMA gather, wave/code
    const int tid = threadIdx.x;
    const int lane = tid & 63, wave = tid >> 6;
    const int k = (int)(blockIdx.x - 2048) * 4 + wave;
    const unsigned n0 = offs[k], nk = cnt[k];
    float S0a = 0.f, S0b = 0.f, S0c = 0.f, S0d = 0.f;
    float S1a = 0.f, S1b = 0.f, S1c = 0.f, S1d = 0.f;
    unsigned i = 0;
    for (; i + 4 <= nk; i += 4) {                // 4-way ILP partial sums
      int r0 = rowlist[n0 + i],     r1 = rowlist[n0 + i + 1];
      int r2 = rowlist[n0 + i + 2], r3 = rowlist[n0 + i + 3];
      S0a += xT[(size_t)r0 * 128 + lane];      S1a += xT[(size_t)r0 * 128 + lane + 64];
      S0b += xT[(size_t)r1 * 128 + lane];      S1b += xT[(size_t)r1 * 128 + lane + 64];
      S0c += xT[(size_t)r2 * 128 + lane];      S1c += xT[(size_t)r2 * 128 + lane + 64];
      S0d += xT[(size_t)r3 * 128 + lane];      S1d += xT[(size_t)r3 * 128 + lane + 64];
    }
    for (; i < nk; ++i) {
      int r = rowlist[n0 + i];
      S0a += xT[(size_t)r * 128 + lane];
      S1a += xT[(size_t)r * 128 + lane + 64];
    }
    float S0 = (S0a + S0b) + (S0c + S0d);
    float S1 = (S1a + S1b) + (S1c + S1d);
    const float omd = (float)(1.0 - 0.99);
    float cf = (float)nk + 1e-12f;
    outw[(size_t)k * 128 + lane]      = 0.99f * w[(size_t)k * 128 + lane]      + omd * (S0 / cf);
    outw[(size_t)k * 128 + lane + 64] = 0.99f * w[(size_t)k * 128 + lane + 64] + omd * (S1 / cf);
  }
}

// ---------------------------------------------------------------------------
extern "C" void kernel_launch(void* const* d_in, const int* in_sizes, int n_in,
                              void* d_out, int out_size, void* d_ws, size_t ws_size,
                              hipStream_t stream) {
  const float* enc = (const float*)d_in[0];      // [16,128,32,32]
  const float* w   = (const float*)d_in[1];      // [8192,128]
  float* out = (float*)d_out;
  float* out_ids = out;                          // 16384 (ids as float)
  float* out_q   = out + N_ROWS;                 // 2097152
  float* out_w   = out + N_ROWS + N_ROWS * C_DIM;// 1048576

  char* ws = (char*)d_ws;
  _Float16* Ap  = (_Float16*)(ws);                         //  0 .. 4194304
  _Float16* Bp  = (_Float16*)(ws + 4194304);               //  .. 6291456
  float* xnorm  = (float*)(ws + 6291456);                  //  .. 6356992
  float* wnorm  = (float*)(ws + 6356992);                  //  .. 6389760
  float* pd1    = (float*)(ws + 6389760);                  // 4 MB
  float* pd2    = (float*)(ws + 10584064);                 // 4 MB
  int* ids      = (int*)(ws + 18972672);                   // 64 KB
  int* fulll    = (int*)(ws + 19038208);                   // 64 KB
  unsigned* items = (unsigned*)(ws + 19103744);            // 1 MB
  unsigned* icount = (unsigned*)(ws + 20152324);           // ctrl
  unsigned* fcount = (unsigned*)(ws + 20152328);
  unsigned* cnt    = (unsigned*)(ws + 20152336);           // 32 KB (int counts)
  unsigned* offs   = (unsigned*)(ws + 20185104);           // 32 KB
  unsigned long long* keys = (unsigned long long*)(ws + 20250640); // 128 KB
  int* rowlist  = (int*)(ws + 20381712);                   // 64 KB
  float* xT     = (float*)(ws + 20447248);                 // 8 MB .. 28835856
  (void)in_sizes; (void)n_in; (void)out_size; (void)ws_size;

  // no memset node: icount/fcount zeroed in gemm; keys+cnt init in classify

  prep<<<384, 256, 0, stream>>>(enc, w, Ap, Bp, xT, xnorm, wnorm);
  gemm_argmin<<<dim3(8, N_ROWS / 128), 512, 0, stream>>>(
      Ap, Bp, wnorm, pd1, pd2, icount, fcount);
  classify<<<N_ROWS * 4 / 256, 256, 0, stream>>>(
      pd1, pd2, xnorm, ids, items, icount, fulll, fcount, keys, cnt);
  refine<<<2048, 256, 0, stream>>>(enc, w, wnorm, items, icount, fulll, fcount,
                                   keys);
  resolve_ids<<<N_ROWS / 256, 256, 0, stream>>>(keys, ids, cnt, out_ids);
  scanfill<<<1, 256, 0, stream>>>(cnt, ids, offs, rowlist);
  qsum_final<<<2048 + K_CODES / 4, 256, 0, stream>>>(
      enc, w, ids, cnt, offs, rowlist, xT, out_q, out_w);
}

// Round 7
// 229.464 us; speedup vs baseline: 1.0863x; 1.0863x over previous
//
#include <hip/hip_runtime.h>
#include <stdint.h>
#include <stddef.h>

// ---------------------------------------------------------------------------
// VQ-VAE quantizer, MI355X.  dist(n,k) = ||x||^2 + ||w_k||^2 - 2 x.w_k.
// f16 GEMM (KD=128), fragment-linear A/B.
// Refine (R4-proven): per-row threshold T = d1~ + 2E over 64 col-groups of
// 128 codes; group top-1s within T are candidates; any group top-2 within T
// -> exact full rescan.  Exact compares via u64 atomicMin keys.
// R12: index-embedded pure min/max top-2 network in the gemm epilogue.
// R16: group fragments staged via global_load_lds (dbuf) -> gemm ~59 us.
// R17: memset folded into gemm; pc1 eliminated (idx bits in pd1 mantissa);
// scan+fill merged; qsum q-path float4.  Node-removal = no effect (theory
// falsified); wm=0.125 constant bound = refine regression 77 us.
// R18 (this round): exact wnmax restored WITHOUT a node: prep w-blocks
// wave-reduce their 64 norms -> wnmax128[block] (plain store); classify
// block-reduces the 128 floats.  refine reads x from xT (contiguous fp32)
// + xnorm instead of 4KB-strided enc re-reads + serial norm recompute
// (ordering safe: each row is exclusively phase-A or phase-B, xn is a
// per-row additive constant -> candidate ranking unchanged).
// ---------------------------------------------------------------------------

#define N_ROWS   16384      // B*H*W = 16*32*32
#define K_CODES  8192
#define C_DIM    128

typedef _Float16 f16x8 __attribute__((ext_vector_type(8)));
typedef float    f32x4 __attribute__((ext_vector_type(4)));

// ---------------- fused prep: blocks [0,256) pack x (+fp32 xT), [256,384) w
// Fragment-linear layout: half P[tile16 T=i>>4][kchunk C=c>>5][lane][8]
//   lane = (i&15) + 16*((c&31)>>3), elem j = c&7  (valid as MFMA A or B frag)
__global__ __launch_bounds__(256) void prep(const float* __restrict__ enc,
                                            const float* __restrict__ w,
                                            _Float16* __restrict__ Ap,
                                            _Float16* __restrict__ Bp,
                                            float* __restrict__ xT,
                                            float* __restrict__ xnorm,
                                            float* __restrict__ wnorm,
                                            float* __restrict__ wnmax128) {
  __shared__ float t[128][65];
  const int tid = threadIdx.x;
  if (blockIdx.x < 256) {                        // ---- x path
    const int b = blockIdx.x >> 4;
    const int hw0 = (blockIdx.x & 15) << 6;
    #pragma unroll
    for (int i = 0; i < 32; ++i) {
      int idx = i * 256 + tid;
      int c = idx >> 6, hwl = idx & 63;
      t[c][hwl] = enc[((size_t)(b * 128 + c) << 10) + hw0 + hwl];
    }
    __syncthreads();
    const int r = tid >> 2, sub = tid & 3;       // row-in-block, k-chunk
    const int n = (b << 10) + hw0 + r;
    const int R = n >> 4, m = n & 15;
    float s = 0.f;
    #pragma unroll
    for (int q = 0; q < 4; ++q) {
      f16x8 hv;
      float vv[8];
      #pragma unroll
      for (int e = 0; e < 8; ++e) {
        float v = t[sub * 32 + q * 8 + e][r];
        vv[e] = v;
        s += v * v;
        hv[e] = (_Float16)v;
      }
      *(f16x8*)(Ap + ((size_t)(R * 4 + sub) * 64 + (m + 16 * q)) * 8) = hv;
      *(float4*)(xT + (size_t)n * 128 + sub * 32 + q * 8) =
          (float4){vv[0], vv[1], vv[2], vv[3]};
      *(float4*)(xT + (size_t)n * 128 + sub * 32 + q * 8 + 4) =
          (float4){vv[4], vv[5], vv[6], vv[7]};
    }
    s += __shfl_xor(s, 1);
    s += __shfl_xor(s, 2);
    if (sub == 0) xnorm[n] = s;
  } else {                                       // ---- w path
    __shared__ float wred[4];
    const int kk = (blockIdx.x - 256) * 64 + (tid >> 2), sub = tid & 3;
    const int R = kk >> 4, m = kk & 15;
    const float* base = w + (size_t)kk * C_DIM + sub * 32;
    float s = 0.f;
    #pragma unroll
    for (int q = 0; q < 4; ++q) {
      f16x8 hv;
      float4 va = *(const float4*)(base + q * 8);
      float4 vb = *(const float4*)(base + q * 8 + 4);
      float vv[8] = {va.x, va.y, va.z, va.w, vb.x, vb.y, vb.z, vb.w};
      #pragma unroll
      for (int e = 0; e < 8; ++e) { s += vv[e] * vv[e]; hv[e] = (_Float16)vv[e]; }
      *(f16x8*)(Bp + ((size_t)(R * 4 + sub) * 64 + (m + 16 * q)) * 8) = hv;
    }
    s += __shfl_xor(s, 1);                       // after: all 4 lanes of the
    s += __shfl_xor(s, 2);                       //  quad hold norm(kk)
    if (sub == 0) wnorm[kk] = s;
    float wx = s;                                // block max of 64 norms
    #pragma unroll
    for (int st = 1; st <= 32; st <<= 1) wx = fmaxf(wx, __shfl_xor(wx, st));
    if ((tid & 63) == 0) wred[tid >> 6] = wx;
    __syncthreads();
    if (tid == 0)
      wnmax128[blockIdx.x - 256] =
          fmaxf(fmaxf(wred[0], wred[1]), fmaxf(wred[2], wred[3]));
  }
}

// ---------------- main GEMM + per-(row,128col-group) top-2 -----------------
// Grid (8 colsplits, 128 rowblocks), 512 thr = 8 waves.  Wave tile: 16 rows
// (B operand) x 128 codes (8 A tiles) per group.  Code fragments for the
// group (32 KB, contiguous in Bp) staged ONCE per block into LDS via
// global_load_lds (dbuf), shared by all 8 waves.  mfma(a=codes, b=rows):
// D col = lane&15 = x-row, D row = 4q+r = code.  Lane owns 1 row x 32
// codes per group.  Scan: embed in-group idx into low mantissa bits
// (r@[1:0], tj@[4:2], q@[6:5]), pure min/max top-2 network + 2-value shfl
// reduce.  pd1/pd2 stored RAW (no +xn; idx bits live in pd1's mantissa —
// classify decodes).  Ties within 2E route to the exact path downstream.
__global__ __launch_bounds__(512) void gemm_argmin(
    const _Float16* __restrict__ Ap, const _Float16* __restrict__ Bp,
    const float* __restrict__ wnorm,
    float* __restrict__ pd1, float* __restrict__ pd2,
    unsigned* __restrict__ icount, unsigned* __restrict__ fcount)
{
  __shared__ _Float16 sbuf[2][16384];            // 2 x 32 KB fragment buffers
  const int tid = threadIdx.x;
  const int lane = tid & 63, wave = tid >> 6;    // 8 waves
  const int m = lane & 15, q = lane >> 4;
  const int cs = blockIdx.x;                     // col slice (1024 codes)
  const int row0 = blockIdx.y * 128;
  const int Tr = blockIdx.y * 8 + wave;          // wave's 16-row tile

  if (cs == 0 && blockIdx.y == 0 && tid == 0) {  // ctrl zero (pre-classify)
    *icount = 0u; *fcount = 0u;
  }

  // stage group itn's 32 fragments (32 KB contiguous) into sbuf[b]
#define STAGE(b, itn) do {                                                   \
    const size_t bh_ = ((size_t)((cs * 64 + (itn) * 8) * 4) << 9);           \
    _Pragma("unroll")                                                        \
    for (int r_ = 0; r_ < 4; ++r_) {                                         \
      __builtin_amdgcn_global_load_lds(                                      \
          (const __attribute__((address_space(1))) void*)                    \
              (Bp + bh_ + ((size_t)(r_ * 512 + tid) << 3)),                  \
          (__attribute__((address_space(3))) void*)                          \
              (&sbuf[b][(r_ * 512 + tid) << 3]),                             \
          16, 0, 0);                                                         \
    }                                                                        \
  } while (0)

  f16x8 bx[4];                                   // x-row fragments (invariant)
  #pragma unroll
  for (int kc = 0; kc < 4; ++kc)
    bx[kc] = *(const f16x8*)(Ap + (((size_t)Tr * 4 + kc) << 9) + (lane << 3));
  const int row = row0 + wave * 16 + m;
  const unsigned q5 = (unsigned)(q << 5);

  STAGE(0, 0);                                   // prologue stage

  for (int it = 0; it < 8; ++it) {               // ascending col groups
    __syncthreads();                             // buf[it&1] ready (vmcnt
                                                 //  drained by barrier)
    if (it < 7) STAGE((it + 1) & 1, it + 1);     // prefetch next group
    const _Float16* fb = &sbuf[it & 1][0];
    const int T0 = cs * 64 + it * 8;             // code-tile base
    const int g = cs * 8 + it;                   // group index [0,64)
    f32x4 acc[8];
    #pragma unroll
    for (int tj = 0; tj < 8; ++tj) acc[tj] = (f32x4){0.f, 0.f, 0.f, 0.f};
    #pragma unroll
    for (int kc = 0; kc < 4; ++kc) {
      #pragma unroll
      for (int tj = 0; tj < 8; ++tj) {
        f16x8 a = *(const f16x8*)(fb + ((tj * 4 + kc) << 9) + (lane << 3));
        acc[tj] = __builtin_amdgcn_mfma_f32_16x16x32_f16(a, bx[kc], acc[tj], 0, 0, 0);
      }
    }
    // per-tj top-2 of 4 via min/max network, idx embedded in low bits
    float m1t[8], m2t[8];
    #pragma unroll
    for (int tj = 0; tj < 8; ++tj) {
      const int cb = (T0 + tj) * 16 + 4 * q;
      float4 wnq = *(const float4*)(wnorm + cb);
      unsigned b0 = __float_as_uint(fmaf(-2.0f, acc[tj][0], wnq.x)) & 0xFFFFFF80u;
      unsigned b1 = __float_as_uint(fmaf(-2.0f, acc[tj][1], wnq.y)) & 0xFFFFFF80u;
      unsigned b2 = __float_as_uint(fmaf(-2.0f, acc[tj][2], wnq.z)) & 0xFFFFFF80u;
      unsigned b3 = __float_as_uint(fmaf(-2.0f, acc[tj][3], wnq.w)) & 0xFFFFFF80u;
      float v0 = __uint_as_float(b0);
      float v1 = __uint_as_float(b1 | 1u);
      float v2 = __uint_as_float(b2 | 2u);
      float v3 = __uint_as_float(b3 | 3u);
      float l1 = fminf(v0, v1), h1 = fmaxf(v0, v1);
      float l2 = fminf(v2, v3), h2 = fmaxf(v2, v3);
      float mm1 = fminf(l1, l2);
      float mm2 = fminf(fminf(h1, h2), fmaxf(l1, l2));
      m1t[tj] = __uint_as_float(__float_as_uint(mm1) | (unsigned)(tj << 2));
      m2t[tj] = mm2;
    }
    // tournament 8 -> 1 (pure min/max; idx bits ride along)
    #pragma unroll
    for (int st = 1; st < 8; st <<= 1)
      #pragma unroll
      for (int j = 0; j < 8; j += 2 * st) {
        float a1 = m1t[j], b1 = m1t[j + st];
        m2t[j] = fminf(fminf(m2t[j], m2t[j + st]), fmaxf(a1, b1));
        m1t[j] = fminf(a1, b1);
      }
    float d1 = __uint_as_float(__float_as_uint(m1t[0]) | q5);
    float d2 = m2t[0];
    // reduce across q (lanes differing in bits 4,5)
    #pragma unroll
    for (int s = 16; s <= 32; s <<= 1) {
      float o1 = __shfl_xor(d1, s), o2 = __shfl_xor(d2, s);
      d2 = fminf(fminf(d2, o2), fmaxf(d1, o1));
      d1 = fminf(d1, o1);
    }
    if (q == 0) {
      size_t pi = (size_t)g * N_ROWS + row;
      pd1[pi] = d1;                              // raw, idx-embedded
      pd2[pi] = d2;                              // raw value
    }
  }
#undef STAGE
}

// ---------------- classify: threshold-collect over 64 groups ---------------
// 4 lanes/row (16 groups each, pd1 kept in registers), shfl merge for the
// global d1 and full/nc flags.  Decodes candidate codes from pd1's embedded
// mantissa bits (q@[6:5] tj@[4:2] r@[1:0]).  wm = exact max||w||^2 reduced
// from wnmax128.  Also inits keys[] + cnt[].
__global__ __launch_bounds__(256) void classify(
    const float* __restrict__ pd1, const float* __restrict__ pd2,
    const float* __restrict__ xnorm, const float* __restrict__ wnmax128,
    int* __restrict__ ids, unsigned* __restrict__ items,
    unsigned* __restrict__ icount, int* __restrict__ fulll,
    unsigned* __restrict__ fcount, unsigned long long* __restrict__ keys,
    unsigned* __restrict__ cnt)
{
  __shared__ float wred[4];
  const int tid = threadIdx.x;
  const int gidx = blockIdx.x * 256 + tid;
  const int row = gidx >> 2, p = gidx & 3;       // 4 lanes per row (same wave)
  if (p == 0) keys[row] = ~0ull;                 // init for refine/resolve
  if (gidx < K_CODES) cnt[gidx] = 0u;
  // exact wm: block-reduce the 128 per-prep-block maxima
  float wv = wnmax128[tid & 127];
  #pragma unroll
  for (int st = 1; st <= 32; st <<= 1) wv = fmaxf(wv, __shfl_xor(wv, st));
  if ((tid & 63) == 0) wred[tid >> 6] = wv;
  __syncthreads();
  const float wm = fmaxf(fmaxf(wred[0], wred[1]), fmaxf(wred[2], wred[3]));

  float v1[16];
  float lmin = __builtin_inff();
  #pragma unroll
  for (int j = 0; j < 16; ++j) {                 // this lane's 16 group-top1s
    v1[j] = pd1[(size_t)(p * 16 + j) * N_ROWS + row];
    lmin = fminf(lmin, v1[j]);
  }
  lmin = fminf(lmin, __shfl_xor(lmin, 1));       // global d1 across 4 lanes
  lmin = fminf(lmin, __shfl_xor(lmin, 2));
  // eps 5e-4 covers 2x 127ulp(|dd|<=8) mantissa-mask error
  float twoE = 2.0f * (0.0029297f * sqrtf(xnorm[row] * wm) + 5e-4f);
  float T = lmin + twoE;
  bool full = false;
  int nc = 0;
  unsigned cands[6];
  #pragma unroll
  for (int j = 0; j < 16; ++j) {
    size_t i = (size_t)(p * 16 + j) * N_ROWS + row;
    if (pd2[i] <= T) { full = true; }
    else if (v1[j] <= T) {
      if (nc < 6) {
        unsigned ui = __float_as_uint(v1[j]) & 127u;
        unsigned g = (unsigned)(p * 16 + j);
        cands[nc++] = (g << 7) | (((ui >> 2) & 7u) << 4) |
                      ((ui >> 5) << 2) | (ui & 3u);
      } else full = true;
    }
  }
  unsigned fm = full ? 1u : 0u;
  int nct = nc;
  fm |= (unsigned)__shfl_xor((int)fm, 1); nct += __shfl_xor(nct, 1);
  fm |= (unsigned)__shfl_xor((int)fm, 2); nct += __shfl_xor(nct, 2);
  if (nct > 6) fm = 1u;                          // cap (conservative-exact)
  if (fm) {
    if (p == 0) { unsigned fi = atomicAdd(fcount, 1u); fulll[fi] = row; }
  } else if (nct >= 2) {
    if (nc > 0) {
      unsigned base = atomicAdd(icount, (unsigned)nc);
      for (int i2 = 0; i2 < nc; ++i2)
        items[base + i2] = ((unsigned)row << 13) | cands[i2];
    }
  } else if (nc == 1) {                          // nct==1, this lane owns it:
    ids[row] = (int)cands[0];                    // unique group within T ->
  }                                              // its top-1 is exact
}

// ---------------- fused exact refine: items (phase A) + full (phase B) -----
// x rows come from xT (row-contiguous fp32) + xnorm — NOT 4KB-strided enc.
// Safe: each row is exclusively phase-A or phase-B; xn is a per-row
// additive constant so candidate ranking is unaffected.
__global__ __launch_bounds__(256) void refine(
    const float* __restrict__ xT, const float* __restrict__ w,
    const float* __restrict__ xnorm, const float* __restrict__ wnorm,
    const unsigned* __restrict__ items, const unsigned* __restrict__ icount,
    const int* __restrict__ fulll, const unsigned* __restrict__ fcount,
    unsigned long long* __restrict__ keys) {
  const int tid = threadIdx.x;
  const int lane = tid & 63, wave = tid >> 6;
  // ---- phase A: candidate items
  const unsigned ic = *icount;
  for (unsigned i = blockIdx.x * 256 + tid; i < ic; i += gridDim.x * 256) {
    unsigned it = items[i];
    int row = (int)(it >> 13), c = (int)(it & 8191u);
    const float* xb = xT + (size_t)row * C_DIM;
    const float* wk = w + (size_t)c * C_DIM;
    float s = 0.f;
    #pragma unroll 8
    for (int c4 = 0; c4 < 32; ++c4) {
      float4 xv = *(const float4*)(xb + c4 * 4);
      float4 wv = *(const float4*)(wk + c4 * 4);
      s = fmaf(xv.x, wv.x, s);
      s = fmaf(xv.y, wv.y, s);
      s = fmaf(xv.z, wv.z, s);
      s = fmaf(xv.w, wv.w, s);
    }
    float d = (xnorm[row] + wnorm[c]) - 2.0f * s;
    unsigned sb = __float_as_uint(d);
    sb = (sb >> 31) ? ~sb : (sb | 0x80000000u);  // sortable float bits
    unsigned long long key = ((unsigned long long)sb << 32) | (unsigned)c;
    atomicMin(&keys[row], key);                  // tie -> lowest code
  }
  // ---- phase B: full rescans, sliced over the codebook
  __shared__ __align__(16) float xs[128];
  __shared__ unsigned long long red[4];
  const unsigned nitems = *fcount * 8;
  for (unsigned item = blockIdx.x; item < nitems; item += gridDim.x) {
    const int row = fulll[item >> 3];
    const int slice = (int)(item & 7u);
    if (tid < 128)                               // stage x row (coalesced)
      xs[tid] = xT[(size_t)row * C_DIM + tid];
    __syncthreads();
    const float xn = xnorm[row];
    const int k0 = slice * 1024 + tid * 4;
    float S[4];
    #pragma unroll
    for (int j = 0; j < 4; ++j) S[j] = 0.f;
    for (int c4 = 0; c4 < 32; ++c4) {
      float4 xv = *(const float4*)(&xs[c4 * 4]);
      #pragma unroll
      for (int j = 0; j < 4; ++j) {
        float4 wv = *(const float4*)(w + (size_t)(k0 + j) * C_DIM + c4 * 4);
        S[j] = fmaf(xv.x, wv.x, S[j]);
        S[j] = fmaf(xv.y, wv.y, S[j]);
        S[j] = fmaf(xv.z, wv.z, S[j]);
        S[j] = fmaf(xv.w, wv.w, S[j]);
      }
    }
    unsigned long long best = ~0ull;
    #pragma unroll
    for (int j = 0; j < 4; ++j) {
      float d = (xn + wnorm[k0 + j]) - 2.0f * S[j];
      unsigned sb = __float_as_uint(d);
      sb = (sb >> 31) ? ~sb : (sb | 0x80000000u);
      unsigned long long key = ((unsigned long long)sb << 32) | (unsigned)(k0 + j);
      best = best < key ? best : key;
    }
    #pragma unroll
    for (int s = 1; s <= 32; s <<= 1) {          // 64-lane u64 butterfly
      unsigned long long ok = __shfl_xor(best, s);
      best = ok < best ? ok : best;
    }
    if (lane == 0) red[wave] = best;
    __syncthreads();
    if (tid == 0) {
      unsigned long long bk = red[0];
      #pragma unroll
      for (int wv = 1; wv < 4; ++wv) bk = red[wv] < bk ? red[wv] : bk;
      atomicMin(&keys[row], bk);
    }
    __syncthreads();                             // xs reused next item
  }
}

// ---------------- resolve final ids + int counts + out_ids -----------------
__global__ void resolve_ids(const unsigned long long* __restrict__ keys,
                            int* __restrict__ ids, unsigned* __restrict__ cnt,
                            float* __restrict__ out_ids) {
  int row = blockIdx.x * 256 + threadIdx.x;
  unsigned long long k = keys[row];
  int id = (k != ~0ull) ? (int)(unsigned)(k & 0xffffffffu) : ids[row];
  ids[row] = id;
  out_ids[row] = (float)id;
  atomicAdd(&cnt[id], 1u);
}

// ---------------- fused scan+fill: offs/cursor scan + CSR fill (1 block) ---
__global__ __launch_bounds__(256) void scanfill(
    const unsigned* __restrict__ cnt, const int* __restrict__ ids,
    unsigned* __restrict__ offs, int* __restrict__ rowlist) {
  __shared__ unsigned sc[K_CODES];               // 32 KB: offs -> cursor
  __shared__ unsigned tot[256];
  const int tid = threadIdx.x;
  unsigned local[32], run = 0;
  #pragma unroll
  for (int i = 0; i < 32; ++i) { local[i] = run; run += cnt[tid * 32 + i]; }
  tot[tid] = run;
  __syncthreads();
  for (int st = 1; st < 256; st <<= 1) {
    unsigned v = (tid >= st) ? tot[tid - st] : 0u;
    __syncthreads();
    tot[tid] += v;
    __syncthreads();
  }
  unsigned excl = (tid == 0) ? 0u : tot[tid - 1];
  #pragma unroll
  for (int i = 0; i < 32; ++i) {
    unsigned o = excl + local[i];
    offs[tid * 32 + i] = o;                      // global (EMA reads)
    sc[tid * 32 + i] = o;                        // LDS cursor
  }
  __syncthreads();
  for (int r = tid; r < N_ROWS; r += 256) {      // fill via LDS atomics
    unsigned slot = atomicAdd(&sc[ids[r]], 1u);
    rowlist[slot] = r;
  }
}

// ---------------- fused tail: q float4 (blocks<2048) + EMA gather (rest) ---
__global__ __launch_bounds__(256) void qsum_final(
    const float* __restrict__ enc, const float* __restrict__ w,
    const int* __restrict__ ids,
    const unsigned* __restrict__ cnt, const unsigned* __restrict__ offs,
    const int* __restrict__ rowlist, const float* __restrict__ xT,
    float* __restrict__ outq, float* __restrict__ outw) {
  if (blockIdx.x < 2048) {                       // ---- straight-through q
    int e = blockIdx.x * 1024 + threadIdx.x * 4; // linear over enc [B,C,H,W]
    int c = (e >> 10) & 127;
    int b = e >> 17;
    int n = (b << 10) | (e & 1023);              // e..e+3: same b,c
    float4 x = *(const float4*)(enc + e);
    float4 o;
    o.x = x.x + (w[(size_t)ids[n + 0] * C_DIM + c] - x.x);
    o.y = x.y + (w[(size_t)ids[n + 1] * C_DIM + c] - x.y);
    o.z = x.z + (w[(size_t)ids[n + 2] * C_DIM + c] - x.z);
    o.w = x.w + (w[(size_t)ids[n + 3] * C_DIM + c] - x.w);
    *(float4*)(outq + e) = o;
  } else {                                       // ---- EMA gather, wave/code
    const int tid = threadIdx.x;
    const int lane = tid & 63, wave = tid >> 6;
    const int k = (int)(blockIdx.x - 2048) * 4 + wave;
    const unsigned n0 = offs[k], nk = cnt[k];
    float S0a = 0.f, S0b = 0.f, S0c = 0.f, S0d = 0.f;
    float S1a = 0.f, S1b = 0.f, S1c = 0.f, S1d = 0.f;
    unsigned i = 0;
    for (; i + 4 <= nk; i += 4) {                // 4-way ILP partial sums
      int r0 = rowlist[n0 + i],     r1 = rowlist[n0 + i + 1];
      int r2 = rowlist[n0 + i + 2], r3 = rowlist[n0 + i + 3];
      S0a += xT[(size_t)r0 * 128 + lane];      S1a += xT[(size_t)r0 * 128 + lane + 64];
      S0b += xT[(size_t)r1 * 128 + lane];      S1b += xT[(size_t)r1 * 128 + lane + 64];
      S0c += xT[(size_t)r2 * 128 + lane];      S1c += xT[(size_t)r2 * 128 + lane + 64];
      S0d += xT[(size_t)r3 * 128 + lane];      S1d += xT[(size_t)r3 * 128 + lane + 64];
    }
    for (; i < nk; ++i) {
      int r = rowlist[n0 + i];
      S0a += xT[(size_t)r * 128 + lane];
      S1a += xT[(size_t)r * 128 + lane + 64];
    }
    float S0 = (S0a + S0b) + (S0c + S0d);
    float S1 = (S1a + S1b) + (S1c + S1d);
    const float omd = (float)(1.0 - 0.99);
    float cf = (float)nk + 1e-12f;
    outw[(size_t)k * 128 + lane]      = 0.99f * w[(size_t)k * 128 + lane]      + omd * (S0 / cf);
    outw[(size_t)k * 128 + lane + 64] = 0.99f * w[(size_t)k * 128 + lane + 64] + omd * (S1 / cf);
  }
}

// ---------------------------------------------------------------------------
extern "C" void kernel_launch(void* const* d_in, const int* in_sizes, int n_in,
                              void* d_out, int out_size, void* d_ws, size_t ws_size,
                              hipStream_t stream) {
  const float* enc = (const float*)d_in[0];      // [16,128,32,32]
  const float* w   = (const float*)d_in[1];      // [8192,128]
  float* out = (float*)d_out;
  float* out_ids = out;                          // 16384 (ids as float)
  float* out_q   = out + N_ROWS;                 // 2097152
  float* out_w   = out + N_ROWS + N_ROWS * C_DIM;// 1048576

  char* ws = (char*)d_ws;
  _Float16* Ap  = (_Float16*)(ws);                         //  0 .. 4194304
  _Float16* Bp  = (_Float16*)(ws + 4194304);               //  .. 6291456
  float* xnorm  = (float*)(ws + 6291456);                  //  .. 6356992
  float* wnorm  = (float*)(ws + 6356992);                  //  .. 6389760
  float* pd1    = (float*)(ws + 6389760);                  // 4 MB
  float* pd2    = (float*)(ws + 10584064);                 // 4 MB
  float* wnmax128 = (float*)(ws + 14778368);               // 512 B (old pc1)
  int* ids      = (int*)(ws + 18972672);                   // 64 KB
  int* fulll    = (int*)(ws + 19038208);                   // 64 KB
  unsigned* items = (unsigned*)(ws + 19103744);            // 1 MB
  unsigned* icount = (unsigned*)(ws + 20152324);           // ctrl
  unsigned* fcount = (unsigned*)(ws + 20152328);
  unsigned* cnt    = (unsigned*)(ws + 20152336);           // 32 KB (int counts)
  unsigned* offs   = (unsigned*)(ws + 20185104);           // 32 KB
  unsigned long long* keys = (unsigned long long*)(ws + 20250640); // 128 KB
  int* rowlist  = (int*)(ws + 20381712);                   // 64 KB
  float* xT     = (float*)(ws + 20447248);                 // 8 MB .. 28835856
  (void)in_sizes; (void)n_in; (void)out_size; (void)ws_size;

  // no memset node: icount/fcount zeroed in gemm; keys+cnt init in classify;
  // wnmax128 plain-stored by prep (no init needed)

  prep<<<384, 256, 0, stream>>>(enc, w, Ap, Bp, xT, xnorm, wnorm, wnmax128);
  gemm_argmin<<<dim3(8, N_ROWS / 128), 512, 0, stream>>>(
      Ap, Bp, wnorm, pd1, pd2, icount, fcount);
  classify<<<N_ROWS * 4 / 256, 256, 0, stream>>>(
      pd1, pd2, xnorm, wnmax128, ids, items, icount, fulll, fcount, keys, cnt);
  refine<<<2048, 256, 0, stream>>>(xT, w, xnorm, wnorm, items, icount, fulll,
                                   fcount, keys);
  resolve_ids<<<N_ROWS / 256, 256, 0, stream>>>(keys, ids, cnt, out_ids);
  scanfill<<<1, 256, 0, stream>>>(cnt, ids, offs, rowlist);
  qsum_final<<<2048 + K_CODES / 4, 256, 0, stream>>>(
      enc, w, ids, cnt, offs, rowlist, xT, out_q, out_w);
}

// Round 8
// 207.787 us; speedup vs baseline: 1.1996x; 1.1043x over previous
//
#include <hip/hip_runtime.h>
#include <stdint.h>
#include <stddef.h>

// ---------------------------------------------------------------------------
// VQ-VAE quantizer, MI355X.  dist(n,k) = ||x||^2 + ||w_k||^2 - 2 x.w_k.
// f16 GEMM (KD=128), fragment-linear A/B.
// Refine (R4-proven): per-row threshold T = d1~ + 2E over 64 col-groups of
// 128 codes; group top-1s within T are candidates; any group top-2 within T
// -> exact full rescan.  Exact compares via u64 atomicMin keys.
// R12: index-embedded pure min/max top-2 network in the gemm epilogue.
// R16: fragments staged via global_load_lds, shared by 8 waves.
// R17: pc1 eliminated (idx bits in pd1 mantissa); no memset node.
// R18: exact wnmax via wnmax128 (prep block maxima); refine reads xT/xnorm.
// R19 (this round): (a) gemm staging granularity 32 KB group -> 16 KB
// half-group, dbuf 2x16 KB = 32 KB LDS -> 4 blocks/CU (thread-slot max,
// was 2 at 64 KB; occupancy 35% -> cap 100%); acc shrinks 8->4 f32x4;
// scan uses the half+carry merge (R4's carry logic — proven; its failure
// was register blocking, not the carry).  (b) UN-merge scanfill: the 1-CU
// fill was a ~10 us tail regression vs R5's parallel fill_rowlist (R6
// proved nodes are ~free, so the extra node costs nothing).
// ---------------------------------------------------------------------------

#define N_ROWS   16384      // B*H*W = 16*32*32
#define K_CODES  8192
#define C_DIM    128

typedef _Float16 f16x8 __attribute__((ext_vector_type(8)));
typedef float    f32x4 __attribute__((ext_vector_type(4)));

// ---------------- fused prep: blocks [0,256) pack x (+fp32 xT), [256,384) w
// Fragment-linear layout: half P[tile16 T=i>>4][kchunk C=c>>5][lane][8]
//   lane = (i&15) + 16*((c&31)>>3), elem j = c&7  (valid as MFMA A or B frag)
__global__ __launch_bounds__(256) void prep(const float* __restrict__ enc,
                                            const float* __restrict__ w,
                                            _Float16* __restrict__ Ap,
                                            _Float16* __restrict__ Bp,
                                            float* __restrict__ xT,
                                            float* __restrict__ xnorm,
                                            float* __restrict__ wnorm,
                                            float* __restrict__ wnmax128) {
  __shared__ float t[128][65];
  const int tid = threadIdx.x;
  if (blockIdx.x < 256) {                        // ---- x path
    const int b = blockIdx.x >> 4;
    const int hw0 = (blockIdx.x & 15) << 6;
    #pragma unroll
    for (int i = 0; i < 32; ++i) {
      int idx = i * 256 + tid;
      int c = idx >> 6, hwl = idx & 63;
      t[c][hwl] = enc[((size_t)(b * 128 + c) << 10) + hw0 + hwl];
    }
    __syncthreads();
    const int r = tid >> 2, sub = tid & 3;       // row-in-block, k-chunk
    const int n = (b << 10) + hw0 + r;
    const int R = n >> 4, m = n & 15;
    float s = 0.f;
    #pragma unroll
    for (int q = 0; q < 4; ++q) {
      f16x8 hv;
      float vv[8];
      #pragma unroll
      for (int e = 0; e < 8; ++e) {
        float v = t[sub * 32 + q * 8 + e][r];
        vv[e] = v;
        s += v * v;
        hv[e] = (_Float16)v;
      }
      *(f16x8*)(Ap + ((size_t)(R * 4 + sub) * 64 + (m + 16 * q)) * 8) = hv;
      *(float4*)(xT + (size_t)n * 128 + sub * 32 + q * 8) =
          (float4){vv[0], vv[1], vv[2], vv[3]};
      *(float4*)(xT + (size_t)n * 128 + sub * 32 + q * 8 + 4) =
          (float4){vv[4], vv[5], vv[6], vv[7]};
    }
    s += __shfl_xor(s, 1);
    s += __shfl_xor(s, 2);
    if (sub == 0) xnorm[n] = s;
  } else {                                       // ---- w path
    __shared__ float wred[4];
    const int kk = (blockIdx.x - 256) * 64 + (tid >> 2), sub = tid & 3;
    const int R = kk >> 4, m = kk & 15;
    const float* base = w + (size_t)kk * C_DIM + sub * 32;
    float s = 0.f;
    #pragma unroll
    for (int q = 0; q < 4; ++q) {
      f16x8 hv;
      float4 va = *(const float4*)(base + q * 8);
      float4 vb = *(const float4*)(base + q * 8 + 4);
      float vv[8] = {va.x, va.y, va.z, va.w, vb.x, vb.y, vb.z, vb.w};
      #pragma unroll
      for (int e = 0; e < 8; ++e) { s += vv[e] * vv[e]; hv[e] = (_Float16)vv[e]; }
      *(f16x8*)(Bp + ((size_t)(R * 4 + sub) * 64 + (m + 16 * q)) * 8) = hv;
    }
    s += __shfl_xor(s, 1);                       // after: all 4 lanes of the
    s += __shfl_xor(s, 2);                       //  quad hold norm(kk)
    if (sub == 0) wnorm[kk] = s;
    float wx = s;                                // block max of 64 norms
    #pragma unroll
    for (int st = 1; st <= 32; st <<= 1) wx = fmaxf(wx, __shfl_xor(wx, st));
    if ((tid & 63) == 0) wred[tid >> 6] = wx;
    __syncthreads();
    if (tid == 0)
      wnmax128[blockIdx.x - 256] =
          fmaxf(fmaxf(wred[0], wred[1]), fmaxf(wred[2], wred[3]));
  }
}

// ---------------- main GEMM + per-(row,128col-group) top-2 -----------------
// Grid (8 colsplits, 128 rowblocks), 512 thr = 8 waves.  Wave tile: 16 rows
// (B operand) x 128 codes per group, processed as 16 HALF-groups of 4 code
// tiles (16 KB each), staged via global_load_lds into a 2x16 KB dbuf
// (32 KB LDS -> 4 blocks/CU).  mfma(a=codes, b=rows): D col = lane&15 =
// x-row, D row = 4q+r = code.  Scan: idx embedded in low mantissa bits
// (r@[1:0], tj@[4:2], q@[6:5]), per-half min/max top-2 network + carry
// merge across halves + 2-value shfl reduce.  pd1/pd2 stored RAW (idx bits
// in pd1 mantissa; classify decodes).  Near-ties (<2E) -> exact path.
__global__ __launch_bounds__(512) void gemm_argmin(
    const _Float16* __restrict__ Ap, const _Float16* __restrict__ Bp,
    const float* __restrict__ wnorm,
    float* __restrict__ pd1, float* __restrict__ pd2,
    unsigned* __restrict__ icount, unsigned* __restrict__ fcount)
{
  __shared__ _Float16 sbuf[2][8192];             // 2 x 16 KB half-group bufs
  const int tid = threadIdx.x;
  const int lane = tid & 63, wave = tid >> 6;    // 8 waves
  const int m = lane & 15, q = lane >> 4;
  const int cs = blockIdx.x;                     // col slice (1024 codes)
  const int row0 = blockIdx.y * 128;
  const int Tr = blockIdx.y * 8 + wave;          // wave's 16-row tile

  if (cs == 0 && blockIdx.y == 0 && tid == 0) {  // ctrl zero (pre-classify)
    *icount = 0u; *fcount = 0u;
  }

  // stage half-group hgn (4 tiles = 16 KB contiguous) into sbuf[b]
#define STAGE(b, hgn) do {                                                   \
    const size_t bh_ = ((size_t)((cs * 64 + (hgn) * 4) * 4) << 9);           \
    _Pragma("unroll")                                                        \
    for (int r_ = 0; r_ < 2; ++r_) {                                         \
      __builtin_amdgcn_global_load_lds(                                      \
          (const __attribute__((address_space(1))) void*)                    \
              (Bp + bh_ + ((size_t)(r_ * 512 + tid) << 3)),                  \
          (__attribute__((address_space(3))) void*)                          \
              (&sbuf[b][(r_ * 512 + tid) << 3]),                             \
          16, 0, 0);                                                         \
    }                                                                        \
  } while (0)

  f16x8 bx[4];                                   // x-row fragments (invariant)
  #pragma unroll
  for (int kc = 0; kc < 4; ++kc)
    bx[kc] = *(const f16x8*)(Ap + (((size_t)Tr * 4 + kc) << 9) + (lane << 3));
  const int row = row0 + wave * 16 + m;
  const unsigned q5 = (unsigned)(q << 5);

  STAGE(0, 0);                                   // prologue stage

  float c1 = 0.f, c2 = 0.f;                      // group carry (set at half 0)
  for (int hg = 0; hg < 16; ++hg) {              // ascending half-groups
    __syncthreads();                             // buf[hg&1] ready (vmcnt
                                                 //  drained by barrier)
    if (hg < 15) STAGE((hg + 1) & 1, hg + 1);    // prefetch next half
    const _Float16* fb = &sbuf[hg & 1][0];
    const int half = hg & 1;
    f32x4 acc[4];
    #pragma unroll
    for (int t = 0; t < 4; ++t) acc[t] = (f32x4){0.f, 0.f, 0.f, 0.f};
    #pragma unroll
    for (int kc = 0; kc < 4; ++kc) {
      #pragma unroll
      for (int t = 0; t < 4; ++t) {
        f16x8 a = *(const f16x8*)(fb + ((t * 4 + kc) << 9) + (lane << 3));
        acc[t] = __builtin_amdgcn_mfma_f32_16x16x32_f16(a, bx[kc], acc[t], 0, 0, 0);
      }
    }
    // per-tile top-2 of 4 via min/max network, idx embedded in low bits
    float m1t[4], m2t[4];
    #pragma unroll
    for (int t = 0; t < 4; ++t) {
      const int tj = half * 4 + t;               // tile-in-group
      const int cb = (cs * 64 + hg * 4 + t) * 16 + 4 * q;
      float4 wnq = *(const float4*)(wnorm + cb);
      unsigned b0 = __float_as_uint(fmaf(-2.0f, acc[t][0], wnq.x)) & 0xFFFFFF80u;
      unsigned b1 = __float_as_uint(fmaf(-2.0f, acc[t][1], wnq.y)) & 0xFFFFFF80u;
      unsigned b2 = __float_as_uint(fmaf(-2.0f, acc[t][2], wnq.z)) & 0xFFFFFF80u;
      unsigned b3 = __float_as_uint(fmaf(-2.0f, acc[t][3], wnq.w)) & 0xFFFFFF80u;
      float v0 = __uint_as_float(b0);
      float v1 = __uint_as_float(b1 | 1u);
      float v2 = __uint_as_float(b2 | 2u);
      float v3 = __uint_as_float(b3 | 3u);
      float l1 = fminf(v0, v1), h1 = fmaxf(v0, v1);
      float l2 = fminf(v2, v3), h2 = fmaxf(v2, v3);
      float mm1 = fminf(l1, l2);
      float mm2 = fminf(fminf(h1, h2), fmaxf(l1, l2));
      m1t[t] = __uint_as_float(__float_as_uint(mm1) | (unsigned)(tj << 2));
      m2t[t] = mm2;
    }
    // tournament 4 -> 1 (pure min/max; idx bits ride along)
    m2t[0] = fminf(fminf(m2t[0], m2t[1]), fmaxf(m1t[0], m1t[1]));
    m1t[0] = fminf(m1t[0], m1t[1]);
    m2t[2] = fminf(fminf(m2t[2], m2t[3]), fmaxf(m1t[2], m1t[3]));
    m1t[2] = fminf(m1t[2], m1t[3]);
    m2t[0] = fminf(fminf(m2t[0], m2t[2]), fmaxf(m1t[0], m1t[2]));
    m1t[0] = fminf(m1t[0], m1t[2]);
    if (half == 0) {                             // first half: set carry
      c1 = m1t[0]; c2 = m2t[0];
    } else {                                     // second half: merge + emit
      c2 = fminf(fminf(c2, m2t[0]), fmaxf(c1, m1t[0]));
      c1 = fminf(c1, m1t[0]);
      float d1 = __uint_as_float(__float_as_uint(c1) | q5);
      float d2 = c2;
      // reduce across q (lanes differing in bits 4,5)
      #pragma unroll
      for (int s = 16; s <= 32; s <<= 1) {
        float o1 = __shfl_xor(d1, s), o2 = __shfl_xor(d2, s);
        d2 = fminf(fminf(d2, o2), fmaxf(d1, o1));
        d1 = fminf(d1, o1);
      }
      if (q == 0) {
        const int g = cs * 8 + (hg >> 1);        // group index [0,64)
        size_t pi = (size_t)g * N_ROWS + row;
        pd1[pi] = d1;                            // raw, idx-embedded
        pd2[pi] = d2;                            // raw value
      }
    }
  }
#undef STAGE
}

// ---------------- classify: threshold-collect over 64 groups ---------------
// 4 lanes/row (16 groups each, pd1 kept in registers), shfl merge for the
// global d1 and full/nc flags.  Decodes candidate codes from pd1's embedded
// mantissa bits (q@[6:5] tj@[4:2] r@[1:0]).  wm = exact max||w||^2 reduced
// from wnmax128.  Also inits keys[] + cnt[].
__global__ __launch_bounds__(256) void classify(
    const float* __restrict__ pd1, const float* __restrict__ pd2,
    const float* __restrict__ xnorm, const float* __restrict__ wnmax128,
    int* __restrict__ ids, unsigned* __restrict__ items,
    unsigned* __restrict__ icount, int* __restrict__ fulll,
    unsigned* __restrict__ fcount, unsigned long long* __restrict__ keys,
    unsigned* __restrict__ cnt)
{
  __shared__ float wred[4];
  const int tid = threadIdx.x;
  const int gidx = blockIdx.x * 256 + tid;
  const int row = gidx >> 2, p = gidx & 3;       // 4 lanes per row (same wave)
  if (p == 0) keys[row] = ~0ull;                 // init for refine/resolve
  if (gidx < K_CODES) cnt[gidx] = 0u;
  // exact wm: block-reduce the 128 per-prep-block maxima
  float wv = wnmax128[tid & 127];
  #pragma unroll
  for (int st = 1; st <= 32; st <<= 1) wv = fmaxf(wv, __shfl_xor(wv, st));
  if ((tid & 63) == 0) wred[tid >> 6] = wv;
  __syncthreads();
  const float wm = fmaxf(fmaxf(wred[0], wred[1]), fmaxf(wred[2], wred[3]));

  float v1[16];
  float lmin = __builtin_inff();
  #pragma unroll
  for (int j = 0; j < 16; ++j) {                 // this lane's 16 group-top1s
    v1[j] = pd1[(size_t)(p * 16 + j) * N_ROWS + row];
    lmin = fminf(lmin, v1[j]);
  }
  lmin = fminf(lmin, __shfl_xor(lmin, 1));       // global d1 across 4 lanes
  lmin = fminf(lmin, __shfl_xor(lmin, 2));
  // eps 5e-4 covers 2x 127ulp(|dd|<=8) mantissa-mask error
  float twoE = 2.0f * (0.0029297f * sqrtf(xnorm[row] * wm) + 5e-4f);
  float T = lmin + twoE;
  bool full = false;
  int nc = 0;
  unsigned cands[6];
  #pragma unroll
  for (int j = 0; j < 16; ++j) {
    size_t i = (size_t)(p * 16 + j) * N_ROWS + row;
    if (pd2[i] <= T) { full = true; }
    else if (v1[j] <= T) {
      if (nc < 6) {
        unsigned ui = __float_as_uint(v1[j]) & 127u;
        unsigned g = (unsigned)(p * 16 + j);
        cands[nc++] = (g << 7) | (((ui >> 2) & 7u) << 4) |
                      ((ui >> 5) << 2) | (ui & 3u);
      } else full = true;
    }
  }
  unsigned fm = full ? 1u : 0u;
  int nct = nc;
  fm |= (unsigned)__shfl_xor((int)fm, 1); nct += __shfl_xor(nct, 1);
  fm |= (unsigned)__shfl_xor((int)fm, 2); nct += __shfl_xor(nct, 2);
  if (nct > 6) fm = 1u;                          // cap (conservative-exact)
  if (fm) {
    if (p == 0) { unsigned fi = atomicAdd(fcount, 1u); fulll[fi] = row; }
  } else if (nct >= 2) {
    if (nc > 0) {
      unsigned base = atomicAdd(icount, (unsigned)nc);
      for (int i2 = 0; i2 < nc; ++i2)
        items[base + i2] = ((unsigned)row << 13) | cands[i2];
    }
  } else if (nc == 1) {                          // nct==1, this lane owns it:
    ids[row] = (int)cands[0];                    // unique group within T ->
  }                                              // its top-1 is exact
}

// ---------------- fused exact refine: items (phase A) + full (phase B) -----
// x rows come from xT (row-contiguous fp32) + xnorm.  Safe: each row is
// exclusively phase-A or phase-B; xn is a per-row additive constant.
__global__ __launch_bounds__(256) void refine(
    const float* __restrict__ xT, const float* __restrict__ w,
    const float* __restrict__ xnorm, const float* __restrict__ wnorm,
    const unsigned* __restrict__ items, const unsigned* __restrict__ icount,
    const int* __restrict__ fulll, const unsigned* __restrict__ fcount,
    unsigned long long* __restrict__ keys) {
  const int tid = threadIdx.x;
  const int lane = tid & 63, wave = tid >> 6;
  // ---- phase A: candidate items
  const unsigned ic = *icount;
  for (unsigned i = blockIdx.x * 256 + tid; i < ic; i += gridDim.x * 256) {
    unsigned it = items[i];
    int row = (int)(it >> 13), c = (int)(it & 8191u);
    const float* xb = xT + (size_t)row * C_DIM;
    const float* wk = w + (size_t)c * C_DIM;
    float s = 0.f;
    #pragma unroll 8
    for (int c4 = 0; c4 < 32; ++c4) {
      float4 xv = *(const float4*)(xb + c4 * 4);
      float4 wv = *(const float4*)(wk + c4 * 4);
      s = fmaf(xv.x, wv.x, s);
      s = fmaf(xv.y, wv.y, s);
      s = fmaf(xv.z, wv.z, s);
      s = fmaf(xv.w, wv.w, s);
    }
    float d = (xnorm[row] + wnorm[c]) - 2.0f * s;
    unsigned sb = __float_as_uint(d);
    sb = (sb >> 31) ? ~sb : (sb | 0x80000000u);  // sortable float bits
    unsigned long long key = ((unsigned long long)sb << 32) | (unsigned)c;
    atomicMin(&keys[row], key);                  // tie -> lowest code
  }
  // ---- phase B: full rescans, sliced over the codebook
  __shared__ __align__(16) float xs[128];
  __shared__ unsigned long long red[4];
  const unsigned nitems = *fcount * 8;
  for (unsigned item = blockIdx.x; item < nitems; item += gridDim.x) {
    const int row = fulll[item >> 3];
    const int slice = (int)(item & 7u);
    if (tid < 128)                               // stage x row (coalesced)
      xs[tid] = xT[(size_t)row * C_DIM + tid];
    __syncthreads();
    const float xn = xnorm[row];
    const int k0 = slice * 1024 + tid * 4;
    float S[4];
    #pragma unroll
    for (int j = 0; j < 4; ++j) S[j] = 0.f;
    for (int c4 = 0; c4 < 32; ++c4) {
      float4 xv = *(const float4*)(&xs[c4 * 4]);
      #pragma unroll
      for (int j = 0; j < 4; ++j) {
        float4 wv = *(const float4*)(w + (size_t)(k0 + j) * C_DIM + c4 * 4);
        S[j] = fmaf(xv.x, wv.x, S[j]);
        S[j] = fmaf(xv.y, wv.y, S[j]);
        S[j] = fmaf(xv.z, wv.z, S[j]);
        S[j] = fmaf(xv.w, wv.w, S[j]);
      }
    }
    unsigned long long best = ~0ull;
    #pragma unroll
    for (int j = 0; j < 4; ++j) {
      float d = (xn + wnorm[k0 + j]) - 2.0f * S[j];
      unsigned sb = __float_as_uint(d);
      sb = (sb >> 31) ? ~sb : (sb | 0x80000000u);
      unsigned long long key = ((unsigned long long)sb << 32) | (unsigned)(k0 + j);
      best = best < key ? best : key;
    }
    #pragma unroll
    for (int s = 1; s <= 32; s <<= 1) {          // 64-lane u64 butterfly
      unsigned long long ok = __shfl_xor(best, s);
      best = ok < best ? ok : best;
    }
    if (lane == 0) red[wave] = best;
    __syncthreads();
    if (tid == 0) {
      unsigned long long bk = red[0];
      #pragma unroll
      for (int wv = 1; wv < 4; ++wv) bk = red[wv] < bk ? red[wv] : bk;
      atomicMin(&keys[row], bk);
    }
    __syncthreads();                             // xs reused next item
  }
}

// ---------------- resolve final ids + int counts + out_ids -----------------
__global__ void resolve_ids(const unsigned long long* __restrict__ keys,
                            int* __restrict__ ids, unsigned* __restrict__ cnt,
                            float* __restrict__ out_ids) {
  int row = blockIdx.x * 256 + threadIdx.x;
  unsigned long long k = keys[row];
  int id = (k != ~0ull) ? (int)(unsigned)(k & 0xffffffffu) : ids[row];
  ids[row] = id;
  out_ids[row] = (float)id;
  atomicAdd(&cnt[id], 1u);
}

// ---------------- exclusive scan of counts -> offs + cursor (1 block) ------
__global__ __launch_bounds__(256) void scan_offsets(
    const unsigned* __restrict__ cnt,
    unsigned* __restrict__ offs, unsigned* __restrict__ cursor) {
  __shared__ unsigned tot[256];
  const int tid = threadIdx.x;
  unsigned local[32], run = 0;
  #pragma unroll
  for (int i = 0; i < 32; ++i) { local[i] = run; run += cnt[tid * 32 + i]; }
  tot[tid] = run;
  __syncthreads();
  for (int st = 1; st < 256; st <<= 1) {
    unsigned v = (tid >= st) ? tot[tid - st] : 0u;
    __syncthreads();
    tot[tid] += v;
    __syncthreads();
  }
  unsigned excl = (tid == 0) ? 0u : tot[tid - 1];
  #pragma unroll
  for (int i = 0; i < 32; ++i) {
    unsigned o = excl + local[i];
    offs[tid * 32 + i] = o;
    cursor[tid * 32 + i] = o;
  }
}

// ---------------- fill CSR row list (parallel, 64 blocks) ------------------
__global__ void fill_rowlist(const int* __restrict__ ids,
                             unsigned* __restrict__ cursor,
                             int* __restrict__ rowlist) {
  int row = blockIdx.x * 256 + threadIdx.x;
  unsigned slot = atomicAdd(&cursor[ids[row]], 1u);
  rowlist[slot] = row;
}

// ---------------- fused tail: q float4 (blocks<2048) + EMA gather (rest) ---
__global__ __launch_bounds__(256) void qsum_final(
    const float* __restrict__ enc, const float* __restrict__ w,
    const int* __restrict__ ids,
    const unsigned* __restrict__ cnt, const unsigned* __restrict__ offs,
    const int* __restrict__ rowlist, const float* __restrict__ xT,
    float* __restrict__ outq, float* __restrict__ outw) {
  if (blockIdx.x < 2048) {                       // ---- straight-through q
    int e = blockIdx.x * 1024 + threadIdx.x * 4; // linear over enc [B,C,H,W]
    int c = (e >> 10) & 127;
    int b = e >> 17;
    int n = (b << 10) | (e & 1023);              // e..e+3: same b,c
    float4 x = *(const float4*)(enc + e);
    float4 o;
    o.x = x.x + (w[(size_t)ids[n + 0] * C_DIM + c] - x.x);
    o.y = x.y + (w[(size_t)ids[n + 1] * C_DIM + c] - x.y);
    o.z = x.z + (w[(size_t)ids[n + 2] * C_DIM + c] - x.z);
    o.w = x.w + (w[(size_t)ids[n + 3] * C_DIM + c] - x.w);
    *(float4*)(outq + e) = o;
  } else {                                       // ---- EMA gather, wave/code
    const int tid = threadIdx.x;
    const int lane = tid & 63, wave = tid >> 6;
    const int k = (int)(blockIdx.x - 2048) * 4 + wave;
    const unsigned n0 = offs[k], nk = cnt[k];
    float S0a = 0.f, S0b = 0.f, S0c = 0.f, S0d = 0.f;
    float S1a = 0.f, S1b = 0.f, S1c = 0.f, S1d = 0.f;
    unsigned i = 0;
    for (; i + 4 <= nk; i += 4) {                // 4-way ILP partial sums
      int r0 = rowlist[n0 + i],     r1 = rowlist[n0 + i + 1];
      int r2 = rowlist[n0 + i + 2], r3 = rowlist[n0 + i + 3];
      S0a += xT[(size_t)r0 * 128 + lane];      S1a += xT[(size_t)r0 * 128 + lane + 64];
      S0b += xT[(size_t)r1 * 128 + lane];      S1b += xT[(size_t)r1 * 128 + lane + 64];
      S0c += xT[(size_t)r2 * 128 + lane];      S1c += xT[(size_t)r2 * 128 + lane + 64];
      S0d += xT[(size_t)r3 * 128 + lane];      S1d += xT[(size_t)r3 * 128 + lane + 64];
    }
    for (; i < nk; ++i) {
      int r = rowlist[n0 + i];
      S0a += xT[(size_t)r * 128 + lane];
      S1a += xT[(size_t)r * 128 + lane + 64];
    }
    float S0 = (S0a + S0b) + (S0c + S0d);
    float S1 = (S1a + S1b) + (S1c + S1d);
    const float omd = (float)(1.0 - 0.99);
    float cf = (float)nk + 1e-12f;
    outw[(size_t)k * 128 + lane]      = 0.99f * w[(size_t)k * 128 + lane]      + omd * (S0 / cf);
    outw[(size_t)k * 128 + lane + 64] = 0.99f * w[(size_t)k * 128 + lane + 64] + omd * (S1 / cf);
  }
}

// ---------------------------------------------------------------------------
extern "C" void kernel_launch(void* const* d_in, const int* in_sizes, int n_in,
                              void* d_out, int out_size, void* d_ws, size_t ws_size,
                              hipStream_t stream) {
  const float* enc = (const float*)d_in[0];      // [16,128,32,32]
  const float* w   = (const float*)d_in[1];      // [8192,128]
  float* out = (float*)d_out;
  float* out_ids = out;                          // 16384 (ids as float)
  float* out_q   = out + N_ROWS;                 // 2097152
  float* out_w   = out + N_ROWS + N_ROWS * C_DIM;// 1048576

  char* ws = (char*)d_ws;
  _Float16* Ap  = (_Float16*)(ws);                         //  0 .. 4194304
  _Float16* Bp  = (_Float16*)(ws + 4194304);               //  .. 6291456
  float* xnorm  = (float*)(ws + 6291456);                  //  .. 6356992
  float* wnorm  = (float*)(ws + 6356992);                  //  .. 6389760
  float* pd1    = (float*)(ws + 6389760);                  // 4 MB
  float* pd2    = (float*)(ws + 10584064);                 // 4 MB
  float* wnmax128 = (float*)(ws + 14778368);               // 512 B
  int* ids      = (int*)(ws + 18972672);                   // 64 KB
  int* fulll    = (int*)(ws + 19038208);                   // 64 KB
  unsigned* items = (unsigned*)(ws + 19103744);            // 1 MB
  unsigned* icount = (unsigned*)(ws + 20152324);           // ctrl
  unsigned* fcount = (unsigned*)(ws + 20152328);
  unsigned* cnt    = (unsigned*)(ws + 20152336);           // 32 KB (int counts)
  unsigned* offs   = (unsigned*)(ws + 20185104);           // 32 KB
  unsigned* cursor = (unsigned*)(ws + 20217872);           // 32 KB
  unsigned long long* keys = (unsigned long long*)(ws + 20250640); // 128 KB
  int* rowlist  = (int*)(ws + 20381712);                   // 64 KB
  float* xT     = (float*)(ws + 20447248);                 // 8 MB .. 28835856
  (void)in_sizes; (void)n_in; (void)out_size; (void)ws_size;

  // no memset node: icount/fcount zeroed in gemm; keys+cnt init in classify;
  // wnmax128 plain-stored by prep (no init needed)

  prep<<<384, 256, 0, stream>>>(enc, w, Ap, Bp, xT, xnorm, wnorm, wnmax128);
  gemm_argmin<<<dim3(8, N_ROWS / 128), 512, 0, stream>>>(
      Ap, Bp, wnorm, pd1, pd2, icount, fcount);
  classify<<<N_ROWS * 4 / 256, 256, 0, stream>>>(
      pd1, pd2, xnorm, wnmax128, ids, items, icount, fulll, fcount, keys, cnt);
  refine<<<2048, 256, 0, stream>>>(xT, w, xnorm, wnorm, items, icount, fulll,
                                   fcount, keys);
  resolve_ids<<<N_ROWS / 256, 256, 0, stream>>>(keys, ids, cnt, out_ids);
  scan_offsets<<<1, 256, 0, stream>>>(cnt, offs, cursor);
  fill_rowlist<<<N_ROWS / 256, 256, 0, stream>>>(ids, cursor, rowlist);
  qsum_final<<<2048 + K_CODES / 4, 256, 0, stream>>>(
      enc, w, ids, cnt, offs, rowlist, xT, out_q, out_w);
}